// Round 7
// baseline (174.834 us; speedup 1.0000x reference)
//
#include <hip/hip_runtime.h>
#include <math.h>

// ---------------------------------------------------------------------------
// ISTFTHead on gfx950 — fp16 MFMA path, round 18.
//
// Round-17 post-mortem: counted vmcnt changed nothing (gemm2 46.5us, Mfma 17%).
// gemm2 is invariant to occupancy (r16), prefetch (r14), vmcnt schedule (r17)
// => the barrier-lockstep LDS pipeline itself is the floor (2 barriers x 34 kt
// x 24-wave skew, 6 MFMA/wave between barriers).
// Round 18: ELIMINATE LDS + barriers from both GEMM main loops. Operands are
// already in MFMA fragment layout (lane l -> 16B at tile_base + l*16 =
// perfectly coalesced global_load_dwordx4). Intra-block redundancy is only
// 2-way per tile and both readers share L1 -> LDS dedup was pure overhead.
// Per kt per wave: gemm1 8 loads + 16 MFMA, gemm2 5 loads + 6 MFMA; unroll-2
// lets the compiler pipeline loads over MFMAs with counted vmcnt; no sync.
// Epilogues keep small dedicated LDS (gemm1 32KB, gemm2 13KB).
// prep_k, ola_kernel, all layouts byte-identical to round 17.
//
// Fragment order for mfma_f32_16x16x32_f16 (verified rounds 2-10):
//   A tile: elem(lane,j) = A[m = lane&15][k = (lane>>4)*8 + j]
//   B tile: elem(lane,j) = B[k = (lane>>4)*8 + j][n = lane&15]
//   C/D:    row = (lane>>4)*4 + r, col = lane&15
//   lane fragment = 16 B at tile_base + lane*16.
//
// Workspace map (bytes):
//   A2  [0,          35651584)   16384 x 1088 f16, [mb128][kt34][mts8][l][j]
//   B2  [35651584,   36904960)   mirror basis, [nblk6][kt34][nt6][l][j]
//   A1  [37879808,   54657024)   xh fragments (dead after gemm1)
//   B1  [54657024,   55836672)   Wh fragments (dead after gemm1)
//   FL  [37879808,   56754176)   16384 x 576 f16 (overlays A1/B1)
//   FH  [56754176,   73531392)   16384 x 512 f16
// ---------------------------------------------------------------------------

using half8 = __attribute__((ext_vector_type(8))) _Float16;
using f32x4 = __attribute__((ext_vector_type(4))) float;

#define TWO_PI_OVER_1024 0.006135923151542565f

#define OFF_A2 0
#define OFF_B2 35651584UL
#define OFF_A1 37879808UL
#define OFF_B1 54657024UL
#define OFF_FL 37879808UL
#define OFF_FH 56754176UL

__device__ __forceinline__ float hannf(int s) {
    return 0.5f * (1.0f - __cosf(TWO_PI_OVER_1024 * (float)s));
}

// ---------------- merged prep kernel ----------------
// blocks [0,4096)     : x -> A1 (xh fragments)
// blocks [4096,4384)  : W -> B1 (Wh fragments)
// blocks [4384,4690)  : windowed mirror irfft basis -> B2
__global__ __launch_bounds__(256)
void prep_k(const float* __restrict__ x, const float* __restrict__ W,
            _Float16* __restrict__ A1, _Float16* __restrict__ B1,
            _Float16* __restrict__ B2)
{
    const int bid = blockIdx.x;
    if (bid < 4096) {
        // x (16384x512 f32) -> A1, [mblk128][kt16][mts8][l][j]
        const size_t tid = (size_t)bid * 256 + threadIdx.x;      // 1,048,576
        const int l   = (int)(tid & 63);
        const size_t f = tid >> 6;
        const int mts = (int)(f & 7);
        const size_t g = f >> 3;
        const int kt  = (int)(g & 15);
        const int mtb = (int)(g >> 4);
        const int m   = mtb * 128 + mts * 16 + (l & 15);
        const int k0  = kt * 32 + (l >> 4) * 8;
        const float* xp = x + (size_t)m * 512 + k0;
        const float4 v0 = *(const float4*)xp;
        const float4 v1 = *(const float4*)(xp + 4);
        const float vv[8] = {v0.x, v0.y, v0.z, v0.w, v1.x, v1.y, v1.z, v1.w};
        half8 o;
#pragma unroll
        for (int j = 0; j < 8; ++j) o[j] = (_Float16)vv[j];
        *(half8*)(A1 + tid * 8) = o;
    } else if (bid < 4384) {
        // W (512x1026 f32) -> B1, per bx(0..8): tiles 0..3 mag, 4..7 phase.
        const int tid = (bid - 4096) * 256 + threadIdx.x;        // 73,728
        const int l  = tid & 63;
        const int f  = tid >> 6;
        const int t8 = f & 7;
        const int g  = f >> 3;
        const int kt = g & 15;
        const int bx = g >> 4;
        const int side = t8 >> 2;
        const int nt   = t8 & 3;
        const int c    = bx * 64 + nt * 16 + (l & 15);           // [0,576)
        const int k0   = kt * 32 + (l >> 4) * 8;
        const int wcol = side ? (513 + c) : c;
        half8 o;
#pragma unroll
        for (int j = 0; j < 8; ++j) {
            float v = (c < 513) ? W[(size_t)(k0 + j) * 1026 + wcol] : 0.0f;
            o[j] = (_Float16)v;
        }
        *(half8*)(B1 + (size_t)tid * 8) = o;
    } else {
        // basis -> B2, [nblk6][kt34][nt6][l][j]; kk<544 cos, kk>=544 -sin.
        const int tid = (bid - 4384) * 256 + threadIdx.x;        // 78,336
        const int l  = tid & 63;
        const int f  = tid >> 6;
        const int nt = f % 6;
        const int g  = f / 6;
        const int kt = g % 34;
        const int nblk = g / 34;
        const int n  = nblk * 96 + nt * 16 + (l & 15);
        const int kk0 = kt * 32 + (l >> 4) * 8;
        const float win = hannf(n) * (1.0f / 1024.0f);
        half8 o;
#pragma unroll
        for (int j = 0; j < 8; ++j) {
            const int kk = kk0 + j;
            float v = 0.0f;
            if (kk < 544) {
                const int k = kk;
                if (k < 513) {
                    const float coef = (k == 0 || k == 512) ? 1.0f : 2.0f;
                    v = coef * __cosf(TWO_PI_OVER_1024 * (float)((k * n) & 1023)) * win;
                }
            } else {
                const int k = kk - 544;
                if (k < 513) {
                    const float coef = (k == 0 || k == 512) ? 1.0f : 2.0f;
                    v = -coef * __sinf(TWO_PI_OVER_1024 * (float)((k * n) & 1023)) * win;
                }
            }
            o[j] = (_Float16)v;
        }
        *(half8*)(B2 + (size_t)tid * 8) = o;
    }
}

// ---------------- GEMM1: h = xh@Wh + b, fused activation -------------------
// 128m x 128n tile. NO LDS / NO barriers in the main loop: per kt each wave
// loads its 4 A-frags + 4 B-frags directly from global (coalesced 16B/lane,
// 2-way wave redundancy absorbed by L1) and issues 16 MFMA. unroll-2 for
// load/MFMA overlap. Epilogue via dedicated 32KB LDS transpose (round 12).

__global__ __launch_bounds__(256, 3)
void gemm1_k(const _Float16* __restrict__ A, const _Float16* __restrict__ B,
             const float* __restrict__ bias, _Float16* __restrict__ A2)
{
    __shared__ _Float16 SrT[8192];         // 16 KB
    __shared__ _Float16 SiT[8192];         // 16 KB
    const int t = threadIdx.x, w = t >> 6, l = t & 63;

    // XCD-aware swizzle: 1152 blocks, 144 per XCD = 16 mblk x 9 bx.
    const int lin = blockIdx.x;
    const int xcd = lin & 7, slot = lin >> 3;
    const int mblk = xcd * 16 + slot / 9;
    const int bx   = slot % 9;

    const int wm = (w & 1) * 4;            // m-tile base
    const int q  = w >> 1;                 // n-pair index
    const int jt[4] = {2 * q, 2 * q + 1, 4 + 2 * q, 5 + 2 * q};

    f32x4 acc[4][4];                       // [m-tile][0..1 mag | 2..3 phase]
#pragma unroll
    for (int i = 0; i < 4; ++i)
#pragma unroll
        for (int j = 0; j < 4; ++j) acc[i][j] = (f32x4)0.0f;

    const int lane8 = l * 8;
    // A1 [mblk][kt16][mts8][l][j]; B1 [bx][kt16][t8][l][j]
    const _Float16* Ab = A + ((size_t)mblk * 16 * 8) * 512 + lane8;
    const _Float16* Bb = B + ((size_t)bx * 16 * 8) * 512 + lane8;

#pragma unroll 2
    for (int kt = 0; kt < 16; ++kt) {
        half8 a[4], b[4];
#pragma unroll
        for (int i = 0; i < 4; ++i)
            a[i] = *(const half8*)(Ab + ((size_t)kt * 8 + wm + i) * 512);
#pragma unroll
        for (int j = 0; j < 4; ++j)
            b[j] = *(const half8*)(Bb + ((size_t)kt * 8 + jt[j]) * 512);
#pragma unroll
        for (int i = 0; i < 4; ++i)
#pragma unroll
            for (int j = 0; j < 4; ++j)
                acc[i][j] = __builtin_amdgcn_mfma_f32_16x16x32_f16(a[i], b[j], acc[i][j], 0, 0, 0);
    }

    // ---- epilogue: activation -> LDS transpose -> coalesced fragment stores.
    const int r4 = (l >> 4) * 4, c16 = l & 15;
#pragma unroll
    for (int i = 0; i < 4; ++i) {
        const int row0 = (wm + i) * 16 + r4;          // local row base [0,128)
#pragma unroll
        for (int p = 0; p < 2; ++p) {
            const int cl = (2 * q + p) * 16 + c16;    // local col [0,64)
            const int c  = bx * 64 + cl;              // global S col [0,576)
            const bool valid = (c < 513);
            const float bm = valid ? bias[c] : 0.0f;
            const float bp = valid ? bias[513 + c] : 0.0f;
#pragma unroll
            for (int r = 0; r < 4; ++r) {
                float Sr = 0.0f, Si = 0.0f;
                if (valid) {
                    const float mag = fminf(__expf(acc[i][p][r] + bm), 100.0f);
                    const float ph  = acc[i][2 + p][r] + bp;
                    Sr = mag * __cosf(ph);
                    Si = mag * __sinf(ph);
                }
                const int row = row0 + r;
                const int idx = row * 64 + (cl ^ ((row & 7) * 8));
                SrT[idx] = (_Float16)Sr;
                SiT[idx] = (_Float16)Si;
            }
        }
    }
    __syncthreads();

    // 16 fragment tiles per side (kt2l in {0,1} x mts in [0,8)); 4 per wave.
#pragma unroll
    for (int f = 0; f < 4; ++f) {
        const int tau  = w * 4 + f;
        const int kt2l = tau >> 3, mts = tau & 7;
        if (bx * 2 + kt2l < 17) {          // == old c<544 clip (skips bx=8 hi-kt)
            const int row = mts * 16 + (l & 15);
            const int kl  = kt2l * 32 + (l >> 4) * 8;          // [0,64)
            const int idx = row * 64 + (kl ^ ((row & 7) * 8));
            const half8 vr = *(const half8*)&SrT[idx];
            const half8 vi = *(const half8*)&SiT[idx];
            const int ktr = bx * 2 + kt2l;                     // Sr k-tile
            const int kti = 17 + ktr;                          // Si k-tile
            *(half8*)(A2 + ((((size_t)mblk * 34 + ktr) * 8 + mts) * 64 + l) * 8) = vr;
            *(half8*)(A2 + ((((size_t)mblk * 34 + kti) * 8 + mts) * 64 + l) * 8) = vi;
        }
    }
}

// ---------------- GEMM2: mirror-symmetric frames = A2 @ basis ---------------
// 64m x 96n tile. NO LDS / NO barriers in the main loop: per kt each wave
// loads 2 A-frags + 3 B-frags directly from global and issues 6 MFMA.
// Two unroll-2 loops (C half kt<17, D half kt>=17). Epilogue: two-pass
// 13KB-LDS transpose into split FL/FH (64-row variant, round 16).

__global__ __launch_bounds__(256, 4)
void gemm2_k(const _Float16* __restrict__ A, const _Float16* __restrict__ Bas,
             _Float16* __restrict__ FL, _Float16* __restrict__ FH)
{
    __shared__ _Float16 SH[6656];          // 13 KB ([64][104] f16 tile)
    const int t = threadIdx.x, w = t >> 6, l = t & 63;

    // XCD-aware swizzle: 1536 blocks, 192 per XCD = 32 mb64 x 6 nblk.
    const int lin = blockIdx.x;
    const int xcd = lin & 7, slot = lin >> 3;
    const int mb64 = xcd * 32 + slot / 6;   // [0,256)
    const int nblk = slot % 6;              // [0,6)
    const int mb128 = mb64 >> 1;
    const int msub  = (mb64 & 1) * 4;

    const int wm = (w & 1) * 2, wn = (w >> 1) * 3;

    f32x4 accC[2][3], accD[2][3];
#pragma unroll
    for (int i = 0; i < 2; ++i)
#pragma unroll
        for (int j = 0; j < 3; ++j) { accC[i][j] = (f32x4)0.0f; accD[i][j] = (f32x4)0.0f; }

    const int lane16 = l * 8;
    // A2 [mb128][kt34][mts8][l][j]; B2 [nblk][kt34][nt6][l][j]
    const _Float16* Abase = A + (size_t)mb128 * 34 * 8 * 512 + lane16;
    const _Float16* Bbase = Bas + (size_t)nblk * 34 * 6 * 512 + lane16;
    const int am = msub + wm;              // global mts base for this wave

#pragma unroll 2
    for (int kt = 0; kt < 17; ++kt) {
        half8 a[2], b[3];
#pragma unroll
        for (int i = 0; i < 2; ++i)
            a[i] = *(const half8*)(Abase + ((size_t)kt * 8 + am + i) * 512);
#pragma unroll
        for (int j = 0; j < 3; ++j)
            b[j] = *(const half8*)(Bbase + ((size_t)kt * 6 + wn + j) * 512);
#pragma unroll
        for (int i = 0; i < 2; ++i)
#pragma unroll
            for (int j = 0; j < 3; ++j)
                accC[i][j] = __builtin_amdgcn_mfma_f32_16x16x32_f16(a[i], b[j], accC[i][j], 0, 0, 0);
    }
#pragma unroll 2
    for (int kt = 17; kt < 34; ++kt) {
        half8 a[2], b[3];
#pragma unroll
        for (int i = 0; i < 2; ++i)
            a[i] = *(const half8*)(Abase + ((size_t)kt * 8 + am + i) * 512);
#pragma unroll
        for (int j = 0; j < 3; ++j)
            b[j] = *(const half8*)(Bbase + ((size_t)kt * 6 + wn + j) * 512);
#pragma unroll
        for (int i = 0; i < 2; ++i)
#pragma unroll
            for (int j = 0; j < 3; ++j)
                accD[i][j] = __builtin_amdgcn_mfma_f32_16x16x32_f16(a[i], b[j], accD[i][j], 0, 0, 0);
    }

    // ---- epilogue pass 1: FL[m][96*nblk + lcol] = C+D (cols >512 garbage,
    //      never read). Tile [64][104] f16; pad 104 => worst 2-way banks.
    const int r4 = (l >> 4) * 4, c0 = l & 15;
#pragma unroll
    for (int i = 0; i < 2; ++i) {
        const int row = (wm + i) * 16 + r4;
#pragma unroll
        for (int j = 0; j < 3; ++j) {
            const int lcol = (wn + j) * 16 + c0;
#pragma unroll
            for (int r = 0; r < 4; ++r)
                SH[(row + r) * 104 + lcol] = (_Float16)(accC[i][j][r] + accD[i][j][r]);
        }
    }
    __syncthreads();
    for (int qq = t; qq < 768; qq += 256) {             // 64 rows x 12 chunks
        const int row = qq / 12, cc = qq % 12;
        const half8 v = *(const half8*)&SH[row * 104 + cc * 8];
        *(half8*)(FL + (size_t)(mb64 * 64 + row) * 576 + nblk * 96 + cc * 8) = v;
    }
    __syncthreads();

    // ---- epilogue pass 2: FH[m][c] = frame[512+c].
    // c = 512-n (mirror, value C-D) for n in [1,511]; c = 0 (direct, C+D) for
    // n = 512. Per block c-range is contiguous; lcol = c - Cbase.
    const int Cbase = (nblk == 5) ? 0 : (416 - 96 * nblk);
    const int lo = (nblk == 5) ? 0 : 1;
    const int hi = (nblk == 0) ? 95 : ((nblk == 5) ? 32 : 96);
#pragma unroll
    for (int i = 0; i < 2; ++i) {
        const int row = (wm + i) * 16 + r4;
#pragma unroll
        for (int j = 0; j < 3; ++j) {
            const int n = nblk * 96 + (wn + j) * 16 + c0;
#pragma unroll
            for (int r = 0; r < 4; ++r) {
                if (n >= 1 && n <= 511)
                    SH[(row + r) * 104 + (512 - n - Cbase)] =
                        (_Float16)(accC[i][j][r] - accD[i][j][r]);
                else if (n == 512)
                    SH[(row + r) * 104 + 0] =
                        (_Float16)(accC[i][j][r] + accD[i][j][r]);
            }
        }
    }
    __syncthreads();
    for (int qq = t; qq < 832; qq += 256) {             // 64 rows x 13 chunks
        const int row = qq / 13, cc = qq % 13;
        if (8 * cc > hi) continue;
        _Float16* dst = FH + (size_t)(mb64 * 64 + row) * 512 + Cbase + 8 * cc;
        if (8 * cc >= lo && 8 * cc + 7 <= hi) {
            *(half8*)dst = *(const half8*)&SH[row * 104 + cc * 8];
        } else {
#pragma unroll
            for (int e = 0; e < 8; ++e) {
                const int lc = 8 * cc + e;
                if (lc >= lo && lc <= hi) dst[e] = SH[row * 104 + lc];
            }
        }
    }
}

// ---------------- overlap-add + envelope ------------------------------------
// Interior samples (j in [640, 523904)): exactly 4 terms, env == 1.5 exactly
// (75%-overlap hann identity) => 4 coalesced half8 loads, * 2/3.
// Boundary samples: general loop (trig env), matches reference semantics.

__global__ __launch_bounds__(256)
void ola_kernel(const _Float16* __restrict__ FL, const _Float16* __restrict__ FH,
                float* __restrict__ out)
{
    const int gid = blockIdx.x * 256 + threadIdx.x;     // [0, 524288)
    const size_t base = (size_t)gid * 8;
    const int b  = (int)(base >> 19);
    const int j0 = (int)(base & 524287);
    const int n0 = j0 + 384;

    if (j0 >= 640 && j0 < 523904) {
        const int nb = n0 & 255;                        // <= 248, 8-aligned
        const int T  = n0 >> 8;
        const size_t mT = (size_t)b * 2048 + T;
        const half8 v0 = *(const half8*)(FL + (mT    ) * 576 + nb);
        const half8 v1 = *(const half8*)(FL + (mT - 1) * 576 + nb + 256);
        const half8 v2 = *(const half8*)(FH + (mT - 2) * 512 + nb);
        const half8 v3 = *(const half8*)(FH + (mT - 3) * 512 + nb + 256);
        f32x4 o0, o1;
#pragma unroll
        for (int e = 0; e < 4; ++e)
            o0[e] = ((float)v0[e] + (float)v1[e] + (float)v2[e] + (float)v3[e]) * (2.0f / 3.0f);
#pragma unroll
        for (int e = 0; e < 4; ++e)
            o1[e] = ((float)v0[4 + e] + (float)v1[4 + e] + (float)v2[4 + e] + (float)v3[4 + e]) * (2.0f / 3.0f);
        *(f32x4*)(out + base) = o0;
        *(f32x4*)(out + base + 4) = o1;
    } else {
        for (int e = 0; e < 8; ++e) {
            const int n = n0 + e;
            int t_hi = n >> 8;
            if (t_hi > 2047) t_hi = 2047;
            const int t_lo = (n >= 1023) ? ((n - 768) >> 8) : 0;
            float acc = 0.0f, env = 0.0f;
            for (int tt = t_lo; tt <= t_hi; ++tt) {
                const int s = n - (tt << 8);
                const float wv = hannf(s);
                const size_t m = (size_t)b * 2048 + tt;
                const float fv = (s < 512) ? (float)FL[m * 576 + s]
                                           : (float)FH[m * 512 + (s - 512)];
                acc += fv;
                env += wv * wv;
            }
            out[base + e] = acc / env;
        }
    }
}

// ---------------- launch ----------------------------------------------------

extern "C" void kernel_launch(void* const* d_in, const int* in_sizes, int n_in,
                              void* d_out, int out_size, void* d_ws, size_t ws_size,
                              hipStream_t stream)
{
    const float* x = (const float*)d_in[0];   // 16384 x 512
    const float* W = (const float*)d_in[1];   // 512 x 1026
    const float* b = (const float*)d_in[2];   // 1026
    float* out = (float*)d_out;               // 8 x 524288
    char* ws = (char*)d_ws;

    _Float16* A2 = (_Float16*)(ws + OFF_A2);
    _Float16* B2 = (_Float16*)(ws + OFF_B2);
    _Float16* A1 = (_Float16*)(ws + OFF_A1);
    _Float16* B1 = (_Float16*)(ws + OFF_B1);
    _Float16* FL = (_Float16*)(ws + OFF_FL);
    _Float16* FH = (_Float16*)(ws + OFF_FH);

    prep_k<<<4690, 256, 0, stream>>>(x, W, A1, B1, B2);

    gemm1_k<<<1152, 256, 0, stream>>>(A1, B1, b, A2);
    gemm2_k<<<1536, 256, 0, stream>>>(A2, B2, FL, FH);

    ola_kernel<<<out_size / 2048, 256, 0, stream>>>(FL, FH, out);
}

// Round 8
// 164.885 us; speedup vs baseline: 1.0603x; 1.0603x over previous
//
#include <hip/hip_runtime.h>
#include <math.h>

// ---------------------------------------------------------------------------
// ISTFTHead on gfx950 — fp16 MFMA path, round 19.
//
// Round-18 post-mortem: no-LDS/no-barrier gemm2 = 47.4us, SAME as LDS (r16),
// prefetch (r14), counted-vmcnt (r17), at 3 or 6 blocks/CU. gemm2 duration is
// invariant to every scheduling/occupancy/staging structure tried => it sits
// at the per-CU VMEM front-end floor (~1KB-per-instr wave loads through
// TA/L1), not at a schedule-fixable stall. The only faster structure measured
// is the round-13 128-row block (<41.7us, below the 42us harness fills).
// r18 also regressed gemm1 (+9us: 9x B re-reads via L1 vs staged-once LDS).
// Round 19: restore the measured-best configuration exactly (= round 13):
//   gemm1 = round-12 structure, gemm2 = round-13 two-pass FL/FH epilogue,
//   prep/ola = round-13. Expected total 162-166us. Remaining lever beyond
//   this plateau: fuse gemm1->gemm2 to kill the A2 round-trip.
//
// Fragment order for mfma_f32_16x16x32_f16 (verified rounds 2-10):
//   A tile: elem(lane,j) = A[m = lane&15][k = (lane>>4)*8 + j]
//   B tile: elem(lane,j) = B[k = (lane>>4)*8 + j][n = lane&15]
//   C/D:    row = (lane>>4)*4 + r, col = lane&15
//   lane fragment = 16 B at tile_base + lane*16.
//
// Workspace map (bytes):
//   A2  [0,          35651584)   16384 x 1088 f16, [mb128][kt34][mts8][l][j]
//   B2  [35651584,   36904960)   mirror basis, [nblk6][kt34][nt6][l][j]
//   A1  [37879808,   54657024)   xh fragments (dead after gemm1)
//   B1  [54657024,   55836672)   Wh fragments (dead after gemm1)
//   FL  [37879808,   56754176)   16384 x 576 f16 (overlays A1/B1)
//   FH  [56754176,   73531392)   16384 x 512 f16
// ---------------------------------------------------------------------------

using half8 = __attribute__((ext_vector_type(8))) _Float16;
using f32x4 = __attribute__((ext_vector_type(4))) float;

#define TWO_PI_OVER_1024 0.006135923151542565f

#define OFF_A2 0
#define OFF_B2 35651584UL
#define OFF_A1 37879808UL
#define OFF_B1 54657024UL
#define OFF_FL 37879808UL
#define OFF_FH 56754176UL

__device__ __forceinline__ float hannf(int s) {
    return 0.5f * (1.0f - __cosf(TWO_PI_OVER_1024 * (float)s));
}

// async global->LDS, 16B per lane. Global addr per-lane; LDS dest wave-uniform.
__device__ __forceinline__ void stage16(const void* g, void* lds) {
    __builtin_amdgcn_global_load_lds(
        (const __attribute__((address_space(1))) void*)g,
        (__attribute__((address_space(3))) void*)lds,
        16, 0, 0);
}

// ---------------- merged prep kernel ----------------
// blocks [0,4096)     : x -> A1 (xh fragments)
// blocks [4096,4384)  : W -> B1 (Wh fragments)
// blocks [4384,4690)  : windowed mirror irfft basis -> B2
__global__ __launch_bounds__(256)
void prep_k(const float* __restrict__ x, const float* __restrict__ W,
            _Float16* __restrict__ A1, _Float16* __restrict__ B1,
            _Float16* __restrict__ B2)
{
    const int bid = blockIdx.x;
    if (bid < 4096) {
        // x (16384x512 f32) -> A1, [mblk128][kt16][mts8][l][j]
        const size_t tid = (size_t)bid * 256 + threadIdx.x;      // 1,048,576
        const int l   = (int)(tid & 63);
        const size_t f = tid >> 6;
        const int mts = (int)(f & 7);
        const size_t g = f >> 3;
        const int kt  = (int)(g & 15);
        const int mtb = (int)(g >> 4);
        const int m   = mtb * 128 + mts * 16 + (l & 15);
        const int k0  = kt * 32 + (l >> 4) * 8;
        const float* xp = x + (size_t)m * 512 + k0;
        const float4 v0 = *(const float4*)xp;
        const float4 v1 = *(const float4*)(xp + 4);
        const float vv[8] = {v0.x, v0.y, v0.z, v0.w, v1.x, v1.y, v1.z, v1.w};
        half8 o;
#pragma unroll
        for (int j = 0; j < 8; ++j) o[j] = (_Float16)vv[j];
        *(half8*)(A1 + tid * 8) = o;
    } else if (bid < 4384) {
        // W (512x1026 f32) -> B1, per bx(0..8): tiles 0..3 mag, 4..7 phase.
        const int tid = (bid - 4096) * 256 + threadIdx.x;        // 73,728
        const int l  = tid & 63;
        const int f  = tid >> 6;
        const int t8 = f & 7;
        const int g  = f >> 3;
        const int kt = g & 15;
        const int bx = g >> 4;
        const int side = t8 >> 2;
        const int nt   = t8 & 3;
        const int c    = bx * 64 + nt * 16 + (l & 15);           // [0,576)
        const int k0   = kt * 32 + (l >> 4) * 8;
        const int wcol = side ? (513 + c) : c;
        half8 o;
#pragma unroll
        for (int j = 0; j < 8; ++j) {
            float v = (c < 513) ? W[(size_t)(k0 + j) * 1026 + wcol] : 0.0f;
            o[j] = (_Float16)v;
        }
        *(half8*)(B1 + (size_t)tid * 8) = o;
    } else {
        // basis -> B2, [nblk6][kt34][nt6][l][j]; kk<544 cos, kk>=544 -sin.
        const int tid = (bid - 4384) * 256 + threadIdx.x;        // 78,336
        const int l  = tid & 63;
        const int f  = tid >> 6;
        const int nt = f % 6;
        const int g  = f / 6;
        const int kt = g % 34;
        const int nblk = g / 34;
        const int n  = nblk * 96 + nt * 16 + (l & 15);
        const int kk0 = kt * 32 + (l >> 4) * 8;
        const float win = hannf(n) * (1.0f / 1024.0f);
        half8 o;
#pragma unroll
        for (int j = 0; j < 8; ++j) {
            const int kk = kk0 + j;
            float v = 0.0f;
            if (kk < 544) {
                const int k = kk;
                if (k < 513) {
                    const float coef = (k == 0 || k == 512) ? 1.0f : 2.0f;
                    v = coef * __cosf(TWO_PI_OVER_1024 * (float)((k * n) & 1023)) * win;
                }
            } else {
                const int k = kk - 544;
                if (k < 513) {
                    const float coef = (k == 0 || k == 512) ? 1.0f : 2.0f;
                    v = -coef * __sinf(TWO_PI_OVER_1024 * (float)((k * n) & 1023)) * win;
                }
            }
            o[j] = (_Float16)v;
        }
        *(half8*)(B2 + (size_t)tid * 8) = o;
    }
}

// ---------------- GEMM1: h = xh@Wh + b, fused activation -------------------
// Round-12 structure (best measured).

__global__ __launch_bounds__(256, 4)
void gemm1_k(const _Float16* __restrict__ A, const _Float16* __restrict__ B,
             const float* __restrict__ bias, _Float16* __restrict__ A2)
{
    __shared__ _Float16 Ash[2][8 * 512];   // 2 kt x 8 m-tiles (16 KB)
    __shared__ _Float16 Bsh[2][8 * 512];   // 2 kt x 8 n-tiles (16 KB)
    const int t = threadIdx.x, w = t >> 6, l = t & 63;

    // XCD-aware swizzle: 1152 blocks, 144 per XCD = 16 mblk x 9 bx.
    const int lin = blockIdx.x;
    const int xcd = lin & 7, slot = lin >> 3;
    const int mblk = xcd * 16 + slot / 9;
    const int bx   = slot % 9;

    const int wm = (w & 1) * 4;            // m-tile base
    const int q  = w >> 1;                 // n-pair index
    const int jt[4] = {2 * q, 2 * q + 1, 4 + 2 * q, 5 + 2 * q};

    f32x4 acc[4][4];                       // [m-tile][0..1 mag | 2..3 phase]
#pragma unroll
    for (int i = 0; i < 4; ++i)
#pragma unroll
        for (int j = 0; j < 4; ++j) acc[i][j] = (f32x4)0.0f;

    const int lane8 = l * 8;
    const _Float16* Ab = A + ((size_t)mblk * 16 * 8) * 512 + lane8;
    const _Float16* Bb = B + ((size_t)bx * 16 * 8) * 512 + lane8;

    for (int step = 0; step < 8; ++step) {
        const int kt0 = 2 * step;
        __syncthreads();
#pragma unroll
        for (int i = 0; i < 4; ++i) {
            const int s = 4 * w + i;
            const int u = s >> 3, r = s & 7;
            stage16(Ab + ((size_t)(kt0 + u) * 8 + r) * 512, &Ash[u][r * 512]);
            stage16(Bb + ((size_t)(kt0 + u) * 8 + r) * 512, &Bsh[u][r * 512]);
        }
        __syncthreads();

#pragma unroll
        for (int u = 0; u < 2; ++u) {
            half8 a[4], b[4];
#pragma unroll
            for (int i = 0; i < 4; ++i)
                a[i] = *(const half8*)&Ash[u][(wm + i) * 512 + lane8];
#pragma unroll
            for (int j = 0; j < 4; ++j)
                b[j] = *(const half8*)&Bsh[u][jt[j] * 512 + lane8];
#pragma unroll
            for (int i = 0; i < 4; ++i)
#pragma unroll
                for (int j = 0; j < 4; ++j)
                    acc[i][j] = __builtin_amdgcn_mfma_f32_16x16x32_f16(a[i], b[j], acc[i][j], 0, 0, 0);
        }
    }

    // ---- epilogue: activation -> LDS transpose -> coalesced fragment stores.
    _Float16* SrT = &Ash[0][0];            // 8192 f16 = 16 KB
    _Float16* SiT = &Bsh[0][0];            // 8192 f16 = 16 KB

    __syncthreads();                       // all waves done reading Ash/Bsh
    const int r4 = (l >> 4) * 4, c16 = l & 15;
#pragma unroll
    for (int i = 0; i < 4; ++i) {
        const int row0 = (wm + i) * 16 + r4;          // local row base [0,128)
#pragma unroll
        for (int p = 0; p < 2; ++p) {
            const int cl = (2 * q + p) * 16 + c16;    // local col [0,64)
            const int c  = bx * 64 + cl;              // global S col [0,576)
            const bool valid = (c < 513);
            const float bm = valid ? bias[c] : 0.0f;
            const float bp = valid ? bias[513 + c] : 0.0f;
#pragma unroll
            for (int r = 0; r < 4; ++r) {
                float Sr = 0.0f, Si = 0.0f;
                if (valid) {
                    const float mag = fminf(__expf(acc[i][p][r] + bm), 100.0f);
                    const float ph  = acc[i][2 + p][r] + bp;
                    Sr = mag * __cosf(ph);
                    Si = mag * __sinf(ph);
                }
                const int row = row0 + r;
                const int idx = row * 64 + (cl ^ ((row & 7) * 8));
                SrT[idx] = (_Float16)Sr;
                SiT[idx] = (_Float16)Si;
            }
        }
    }
    __syncthreads();

    // 16 fragment tiles per side (kt2l in {0,1} x mts in [0,8)); 4 per wave.
#pragma unroll
    for (int f = 0; f < 4; ++f) {
        const int tau  = w * 4 + f;
        const int kt2l = tau >> 3, mts = tau & 7;
        if (bx * 2 + kt2l < 17) {          // == old c<544 clip (skips bx=8 hi-kt)
            const int row = mts * 16 + (l & 15);
            const int kl  = kt2l * 32 + (l >> 4) * 8;          // [0,64)
            const int idx = row * 64 + (kl ^ ((row & 7) * 8));
            const half8 vr = *(const half8*)&SrT[idx];
            const half8 vi = *(const half8*)&SiT[idx];
            const int ktr = bx * 2 + kt2l;                     // Sr k-tile
            const int kti = 17 + ktr;                          // Si k-tile
            *(half8*)(A2 + ((((size_t)mblk * 34 + ktr) * 8 + mts) * 64 + l) * 8) = vr;
            *(half8*)(A2 + ((((size_t)mblk * 34 + kti) * 8 + mts) * 64 + l) * 8) = vi;
        }
    }
}

// ---------------- GEMM2: mirror-symmetric frames = A2 @ basis ---------------
// Round-13 structure: 2-kt steps, merged 28KB LDS; two-pass FL/FH epilogue.

__device__ __forceinline__ void mma43(const _Float16* __restrict__ As,
                                      const _Float16* __restrict__ Bs,
                                      int wm, int wn, int lane16, f32x4 (&acc)[4][3])
{
    half8 a[4], b[3];
#pragma unroll
    for (int i = 0; i < 4; ++i) a[i] = *(const half8*)&As[(wm + i) * 512 + lane16];
#pragma unroll
    for (int j = 0; j < 3; ++j) b[j] = *(const half8*)&Bs[(wn + j) * 512 + lane16];
#pragma unroll
    for (int i = 0; i < 4; ++i)
#pragma unroll
        for (int j = 0; j < 3; ++j)
            acc[i][j] = __builtin_amdgcn_mfma_f32_16x16x32_f16(a[i], b[j], acc[i][j], 0, 0, 0);
}

__global__ __launch_bounds__(256, 3)
void gemm2_k(const _Float16* __restrict__ A, const _Float16* __restrict__ Bas,
             _Float16* __restrict__ FL, _Float16* __restrict__ FH)
{
    // Merged staging LDS: As = SH[0..8191] ([2][8*512]), Bs = SH[8192..14335]
    // ([2][6*512]). Epilogue reuses SH[0..13311] as a [128][104] f16 tile.
    __shared__ _Float16 SH[14336];         // 28 KB
    _Float16* As0 = SH;
    _Float16* Bs0 = SH + 8192;
    const int t = threadIdx.x, w = t >> 6, l = t & 63;

    // XCD-aware swizzle: 768 blocks, 96 per XCD = 16 mblk x 6 nblk.
    const int lin = blockIdx.x;
    const int xcd = lin & 7, slot = lin >> 3;
    const int mblk = xcd * 16 + slot / 6;   // [0,128)
    const int nblk = slot % 6;              // [0,6)

    const int wm = (w & 1) * 4, wn = (w >> 1) * 3;

    f32x4 accC[4][3], accD[4][3];
#pragma unroll
    for (int i = 0; i < 4; ++i)
#pragma unroll
        for (int j = 0; j < 3; ++j) { accC[i][j] = (f32x4)0.0f; accD[i][j] = (f32x4)0.0f; }

    const int lane16 = l * 8;

    for (int step = 0; step < 17; ++step) {
        const int kt0 = 2 * step;
        __syncthreads();
#pragma unroll
        for (int i = 0; i < 4; ++i) {
            const int ta = 4 * w + i;
            const int u = ta >> 3, mts = ta & 7;
            const _Float16* Ag = A + ((((size_t)mblk * 34 + (kt0 + u)) * 8 + mts) * 512) + lane16;
            stage16(Ag, &As0[u * 4096 + mts * 512]);
        }
#pragma unroll
        for (int i = 0; i < 3; ++i) {
            const int tb = 3 * w + i;
            const int u = tb / 6, nt = tb % 6;
            const _Float16* Bg = Bas + ((((size_t)nblk * 34 + (kt0 + u)) * 6 + nt) * 512) + lane16;
            stage16(Bg, &Bs0[u * 3072 + nt * 512]);
        }
        __syncthreads();

#pragma unroll
        for (int u = 0; u < 2; ++u) {
            const int kt = kt0 + u;
            if (kt < 17) mma43(As0 + u * 4096, Bs0 + u * 3072, wm, wn, lane16, accC);
            else         mma43(As0 + u * 4096, Bs0 + u * 3072, wm, wn, lane16, accD);
        }
    }

    // ---- epilogue pass 1: FL[m][96*nblk + lcol] = C+D (cols >512 garbage,
    //      never read). Tile [128][104] f16; pad 104 => worst 2-way banks.
    const int r4 = (l >> 4) * 4, c0 = l & 15;
    __syncthreads();
#pragma unroll
    for (int i = 0; i < 4; ++i) {
        const int row = (wm + i) * 16 + r4;
#pragma unroll
        for (int j = 0; j < 3; ++j) {
            const int lcol = (wn + j) * 16 + c0;
#pragma unroll
            for (int r = 0; r < 4; ++r)
                SH[(row + r) * 104 + lcol] = (_Float16)(accC[i][j][r] + accD[i][j][r]);
        }
    }
    __syncthreads();
    for (int qq = t; qq < 1536; qq += 256) {            // 128 rows x 12 chunks
        const int row = qq / 12, cc = qq % 12;
        const half8 v = *(const half8*)&SH[row * 104 + cc * 8];
        *(half8*)(FL + (size_t)(mblk * 128 + row) * 576 + nblk * 96 + cc * 8) = v;
    }
    __syncthreads();

    // ---- epilogue pass 2: FH[m][c] = frame[512+c].
    // c = 512-n (mirror, value C-D) for n in [1,511]; c = 0 (direct, C+D) for
    // n = 512. Per block c-range is contiguous; lcol = c - Cbase.
    const int Cbase = (nblk == 5) ? 0 : (416 - 96 * nblk);
    const int lo = (nblk == 5) ? 0 : 1;
    const int hi = (nblk == 0) ? 95 : ((nblk == 5) ? 32 : 96);
#pragma unroll
    for (int i = 0; i < 4; ++i) {
        const int row = (wm + i) * 16 + r4;
#pragma unroll
        for (int j = 0; j < 3; ++j) {
            const int n = nblk * 96 + (wn + j) * 16 + c0;
#pragma unroll
            for (int r = 0; r < 4; ++r) {
                if (n >= 1 && n <= 511)
                    SH[(row + r) * 104 + (512 - n - Cbase)] =
                        (_Float16)(accC[i][j][r] - accD[i][j][r]);
                else if (n == 512)
                    SH[(row + r) * 104 + 0] =
                        (_Float16)(accC[i][j][r] + accD[i][j][r]);
            }
        }
    }
    __syncthreads();
    for (int qq = t; qq < 1664; qq += 256) {            // 128 rows x 13 chunks
        const int row = qq / 13, cc = qq % 13;
        if (8 * cc > hi) continue;
        _Float16* dst = FH + (size_t)(mblk * 128 + row) * 512 + Cbase + 8 * cc;
        if (8 * cc >= lo && 8 * cc + 7 <= hi) {
            *(half8*)dst = *(const half8*)&SH[row * 104 + cc * 8];
        } else {
#pragma unroll
            for (int e = 0; e < 8; ++e) {
                const int lc = 8 * cc + e;
                if (lc >= lo && lc <= hi) dst[e] = SH[row * 104 + lc];
            }
        }
    }
}

// ---------------- overlap-add + envelope ------------------------------------
// Interior samples (j in [640, 523904)): exactly 4 terms, env == 1.5 exactly
// (75%-overlap hann identity) => 4 coalesced half8 loads, * 2/3.
// Boundary samples: general loop (trig env), matches reference semantics.

__global__ __launch_bounds__(256)
void ola_kernel(const _Float16* __restrict__ FL, const _Float16* __restrict__ FH,
                float* __restrict__ out)
{
    const int gid = blockIdx.x * 256 + threadIdx.x;     // [0, 524288)
    const size_t base = (size_t)gid * 8;
    const int b  = (int)(base >> 19);
    const int j0 = (int)(base & 524287);
    const int n0 = j0 + 384;

    if (j0 >= 640 && j0 < 523904) {
        const int nb = n0 & 255;                        // <= 248, 8-aligned
        const int T  = n0 >> 8;
        const size_t mT = (size_t)b * 2048 + T;
        const half8 v0 = *(const half8*)(FL + (mT    ) * 576 + nb);
        const half8 v1 = *(const half8*)(FL + (mT - 1) * 576 + nb + 256);
        const half8 v2 = *(const half8*)(FH + (mT - 2) * 512 + nb);
        const half8 v3 = *(const half8*)(FH + (mT - 3) * 512 + nb + 256);
        f32x4 o0, o1;
#pragma unroll
        for (int e = 0; e < 4; ++e)
            o0[e] = ((float)v0[e] + (float)v1[e] + (float)v2[e] + (float)v3[e]) * (2.0f / 3.0f);
#pragma unroll
        for (int e = 0; e < 4; ++e)
            o1[e] = ((float)v0[4 + e] + (float)v1[4 + e] + (float)v2[4 + e] + (float)v3[4 + e]) * (2.0f / 3.0f);
        *(f32x4*)(out + base) = o0;
        *(f32x4*)(out + base + 4) = o1;
    } else {
        for (int e = 0; e < 8; ++e) {
            const int n = n0 + e;
            int t_hi = n >> 8;
            if (t_hi > 2047) t_hi = 2047;
            const int t_lo = (n >= 1023) ? ((n - 768) >> 8) : 0;
            float acc = 0.0f, env = 0.0f;
            for (int tt = t_lo; tt <= t_hi; ++tt) {
                const int s = n - (tt << 8);
                const float wv = hannf(s);
                const size_t m = (size_t)b * 2048 + tt;
                const float fv = (s < 512) ? (float)FL[m * 576 + s]
                                           : (float)FH[m * 512 + (s - 512)];
                acc += fv;
                env += wv * wv;
            }
            out[base + e] = acc / env;
        }
    }
}

// ---------------- launch ----------------------------------------------------

extern "C" void kernel_launch(void* const* d_in, const int* in_sizes, int n_in,
                              void* d_out, int out_size, void* d_ws, size_t ws_size,
                              hipStream_t stream)
{
    const float* x = (const float*)d_in[0];   // 16384 x 512
    const float* W = (const float*)d_in[1];   // 512 x 1026
    const float* b = (const float*)d_in[2];   // 1026
    float* out = (float*)d_out;               // 8 x 524288
    char* ws = (char*)d_ws;

    _Float16* A2 = (_Float16*)(ws + OFF_A2);
    _Float16* B2 = (_Float16*)(ws + OFF_B2);
    _Float16* A1 = (_Float16*)(ws + OFF_A1);
    _Float16* B1 = (_Float16*)(ws + OFF_B1);
    _Float16* FL = (_Float16*)(ws + OFF_FL);
    _Float16* FH = (_Float16*)(ws + OFF_FH);

    prep_k<<<4690, 256, 0, stream>>>(x, W, A1, B1, B2);

    gemm1_k<<<1152, 256, 0, stream>>>(A1, B1, b, A2);
    gemm2_k<<<768, 256, 0, stream>>>(A2, B2, FL, FH);

    ola_kernel<<<out_size / 2048, 256, 0, stream>>>(FL, FH, out);
}

// Round 9
// 162.128 us; speedup vs baseline: 1.0784x; 1.0170x over previous
//
#include <hip/hip_runtime.h>
#include <math.h>

// ---------------------------------------------------------------------------
// ISTFTHead on gfx950 — fp16 MFMA path, round 20.
//
// Round-19 post-mortem: plateau confirmed (164.9; gemm2 45.5). gemm2 is
// 45.5-48us under LDS/no-LDS, barriers/none, 3 or 6 blocks/CU, drain-0 or
// counted vmcnt — no pipe >35% => structural latency floor for this
// decomposition. Best measured config remains round 12 (162.0), whose gemm2
// (scalar-store epilogue into frames[16384][1024]) ran <41.7us, i.e. >=4us
// faster than the r13+ FL/FH gemm2 (45.5) — the FL/FH split was a net
// regression bought for ola. But ola's env==1.5 fast path never needed FL/FH:
// interior taps sit at s = nb, nb+256, nb+512, nb+768 inside ONE frame row,
// all 8-aligned -> half8-loadable from the round-12 frames layout directly.
// Round 20 = round-12 bytes verbatim, with only ola replaced:
//  * interior (j0 in [640,523904)): 4x half8 from one frames row pattern,
//    sum * 2/3 (75%-overlap hann identity, env == 1.5 exactly), f32x4 stores.
//  * boundary: round-12 general loop verbatim.
//
// Fragment order for mfma_f32_16x16x32_f16 (verified rounds 2-10):
//   A tile: elem(lane,j) = A[m = lane&15][k = (lane>>4)*8 + j]
//   B tile: elem(lane,j) = B[k = (lane>>4)*8 + j][n = lane&15]
//   C/D:    row = (lane>>4)*4 + r, col = lane&15
//   lane fragment = 16 B at tile_base + lane*16.
//
// Workspace map (bytes):
//   A2  [0,          35651584)   16384 x 1088 f16, [mb128][kt34][mts8][l][j]
//   B2  [35651584,   36904960)   mirror basis, [nblk6][kt34][nt6][l][j]
//   A1  [37879808,   54657024)   xh,  [mblk128][kt16][mts8][l][j]
//   B1  [54657024,   55836672)   Wh,  [bx9][kt16][t8][l][j]
//   frames [37879808, 71434240)  16384 x 1024 f16 (overlays A1+B1 — dead by gemm2)
// ---------------------------------------------------------------------------

using half8 = __attribute__((ext_vector_type(8))) _Float16;
using f32x4 = __attribute__((ext_vector_type(4))) float;

#define TWO_PI_OVER_1024 0.006135923151542565f

#define OFF_A2 0
#define OFF_B2 35651584UL
#define OFF_A1 37879808UL
#define OFF_B1 54657024UL
#define OFF_FR 37879808UL

__device__ __forceinline__ float hannf(int s) {
    return 0.5f * (1.0f - __cosf(TWO_PI_OVER_1024 * (float)s));
}

// async global->LDS, 16B per lane. Global addr per-lane; LDS dest wave-uniform.
__device__ __forceinline__ void stage16(const void* g, void* lds) {
    __builtin_amdgcn_global_load_lds(
        (const __attribute__((address_space(1))) void*)g,
        (__attribute__((address_space(3))) void*)lds,
        16, 0, 0);
}

// ---------------- merged prep kernel ----------------
// blocks [0,4096)     : x -> A1 (xh fragments)
// blocks [4096,4384)  : W -> B1 (Wh fragments)
// blocks [4384,4690)  : windowed mirror irfft basis -> B2
__global__ __launch_bounds__(256)
void prep_k(const float* __restrict__ x, const float* __restrict__ W,
            _Float16* __restrict__ A1, _Float16* __restrict__ B1,
            _Float16* __restrict__ B2)
{
    const int bid = blockIdx.x;
    if (bid < 4096) {
        // x (16384x512 f32) -> A1, [mblk128][kt16][mts8][l][j]
        const size_t tid = (size_t)bid * 256 + threadIdx.x;      // 1,048,576
        const int l   = (int)(tid & 63);
        const size_t f = tid >> 6;
        const int mts = (int)(f & 7);
        const size_t g = f >> 3;
        const int kt  = (int)(g & 15);
        const int mtb = (int)(g >> 4);
        const int m   = mtb * 128 + mts * 16 + (l & 15);
        const int k0  = kt * 32 + (l >> 4) * 8;
        const float* xp = x + (size_t)m * 512 + k0;
        const float4 v0 = *(const float4*)xp;
        const float4 v1 = *(const float4*)(xp + 4);
        const float vv[8] = {v0.x, v0.y, v0.z, v0.w, v1.x, v1.y, v1.z, v1.w};
        half8 o;
#pragma unroll
        for (int j = 0; j < 8; ++j) o[j] = (_Float16)vv[j];
        *(half8*)(A1 + tid * 8) = o;
    } else if (bid < 4384) {
        // W (512x1026 f32) -> B1, per bx(0..8): tiles 0..3 mag, 4..7 phase.
        const int tid = (bid - 4096) * 256 + threadIdx.x;        // 73,728
        const int l  = tid & 63;
        const int f  = tid >> 6;
        const int t8 = f & 7;
        const int g  = f >> 3;
        const int kt = g & 15;
        const int bx = g >> 4;
        const int side = t8 >> 2;
        const int nt   = t8 & 3;
        const int c    = bx * 64 + nt * 16 + (l & 15);           // [0,576)
        const int k0   = kt * 32 + (l >> 4) * 8;
        const int wcol = side ? (513 + c) : c;
        half8 o;
#pragma unroll
        for (int j = 0; j < 8; ++j) {
            float v = (c < 513) ? W[(size_t)(k0 + j) * 1026 + wcol] : 0.0f;
            o[j] = (_Float16)v;
        }
        *(half8*)(B1 + (size_t)tid * 8) = o;
    } else {
        // basis -> B2, [nblk6][kt34][nt6][l][j]; kk<544 cos, kk>=544 -sin.
        const int tid = (bid - 4384) * 256 + threadIdx.x;        // 78,336
        const int l  = tid & 63;
        const int f  = tid >> 6;
        const int nt = f % 6;
        const int g  = f / 6;
        const int kt = g % 34;
        const int nblk = g / 34;
        const int n  = nblk * 96 + nt * 16 + (l & 15);
        const int kk0 = kt * 32 + (l >> 4) * 8;
        const float win = hannf(n) * (1.0f / 1024.0f);
        half8 o;
#pragma unroll
        for (int j = 0; j < 8; ++j) {
            const int kk = kk0 + j;
            float v = 0.0f;
            if (kk < 544) {
                const int k = kk;
                if (k < 513) {
                    const float coef = (k == 0 || k == 512) ? 1.0f : 2.0f;
                    v = coef * __cosf(TWO_PI_OVER_1024 * (float)((k * n) & 1023)) * win;
                }
            } else {
                const int k = kk - 544;
                if (k < 513) {
                    const float coef = (k == 0 || k == 512) ? 1.0f : 2.0f;
                    v = -coef * __sinf(TWO_PI_OVER_1024 * (float)((k * n) & 1023)) * win;
                }
            }
            o[j] = (_Float16)v;
        }
        *(half8*)(B2 + (size_t)tid * 8) = o;
    }
}

// ---------------- GEMM1: h = xh@Wh + b, fused activation -------------------
// Round-12 structure (best measured).

__global__ __launch_bounds__(256, 4)
void gemm1_k(const _Float16* __restrict__ A, const _Float16* __restrict__ B,
             const float* __restrict__ bias, _Float16* __restrict__ A2)
{
    __shared__ _Float16 Ash[2][8 * 512];   // 2 kt x 8 m-tiles (16 KB)
    __shared__ _Float16 Bsh[2][8 * 512];   // 2 kt x 8 n-tiles (16 KB)
    const int t = threadIdx.x, w = t >> 6, l = t & 63;

    // XCD-aware swizzle: 1152 blocks, 144 per XCD = 16 mblk x 9 bx.
    const int lin = blockIdx.x;
    const int xcd = lin & 7, slot = lin >> 3;
    const int mblk = xcd * 16 + slot / 9;
    const int bx   = slot % 9;

    const int wm = (w & 1) * 4;            // m-tile base
    const int q  = w >> 1;                 // n-pair index
    const int jt[4] = {2 * q, 2 * q + 1, 4 + 2 * q, 5 + 2 * q};

    f32x4 acc[4][4];                       // [m-tile][0..1 mag | 2..3 phase]
#pragma unroll
    for (int i = 0; i < 4; ++i)
#pragma unroll
        for (int j = 0; j < 4; ++j) acc[i][j] = (f32x4)0.0f;

    const int lane8 = l * 8;
    const _Float16* Ab = A + ((size_t)mblk * 16 * 8) * 512 + lane8;
    const _Float16* Bb = B + ((size_t)bx * 16 * 8) * 512 + lane8;

    for (int step = 0; step < 8; ++step) {
        const int kt0 = 2 * step;
        __syncthreads();
#pragma unroll
        for (int i = 0; i < 4; ++i) {
            const int s = 4 * w + i;
            const int u = s >> 3, r = s & 7;
            stage16(Ab + ((size_t)(kt0 + u) * 8 + r) * 512, &Ash[u][r * 512]);
            stage16(Bb + ((size_t)(kt0 + u) * 8 + r) * 512, &Bsh[u][r * 512]);
        }
        __syncthreads();

#pragma unroll
        for (int u = 0; u < 2; ++u) {
            half8 a[4], b[4];
#pragma unroll
            for (int i = 0; i < 4; ++i)
                a[i] = *(const half8*)&Ash[u][(wm + i) * 512 + lane8];
#pragma unroll
            for (int j = 0; j < 4; ++j)
                b[j] = *(const half8*)&Bsh[u][jt[j] * 512 + lane8];
#pragma unroll
            for (int i = 0; i < 4; ++i)
#pragma unroll
                for (int j = 0; j < 4; ++j)
                    acc[i][j] = __builtin_amdgcn_mfma_f32_16x16x32_f16(a[i], b[j], acc[i][j], 0, 0, 0);
        }
    }

    // ---- epilogue: activation -> LDS transpose -> coalesced fragment stores.
    _Float16* SrT = &Ash[0][0];            // 8192 f16 = 16 KB
    _Float16* SiT = &Bsh[0][0];            // 8192 f16 = 16 KB

    __syncthreads();                       // all waves done reading Ash/Bsh
    const int r4 = (l >> 4) * 4, c16 = l & 15;
#pragma unroll
    for (int i = 0; i < 4; ++i) {
        const int row0 = (wm + i) * 16 + r4;          // local row base [0,128)
#pragma unroll
        for (int p = 0; p < 2; ++p) {
            const int cl = (2 * q + p) * 16 + c16;    // local col [0,64)
            const int c  = bx * 64 + cl;              // global S col [0,576)
            const bool valid = (c < 513);
            const float bm = valid ? bias[c] : 0.0f;
            const float bp = valid ? bias[513 + c] : 0.0f;
#pragma unroll
            for (int r = 0; r < 4; ++r) {
                float Sr = 0.0f, Si = 0.0f;
                if (valid) {
                    const float mag = fminf(__expf(acc[i][p][r] + bm), 100.0f);
                    const float ph  = acc[i][2 + p][r] + bp;
                    Sr = mag * __cosf(ph);
                    Si = mag * __sinf(ph);
                }
                const int row = row0 + r;
                const int idx = row * 64 + (cl ^ ((row & 7) * 8));
                SrT[idx] = (_Float16)Sr;
                SiT[idx] = (_Float16)Si;
            }
        }
    }
    __syncthreads();

    // 16 fragment tiles per side (kt2l in {0,1} x mts in [0,8)); 4 per wave.
#pragma unroll
    for (int f = 0; f < 4; ++f) {
        const int tau  = w * 4 + f;
        const int kt2l = tau >> 3, mts = tau & 7;
        if (bx * 2 + kt2l < 17) {          // == old c<544 clip (skips bx=8 hi-kt)
            const int row = mts * 16 + (l & 15);
            const int kl  = kt2l * 32 + (l >> 4) * 8;          // [0,64)
            const int idx = row * 64 + (kl ^ ((row & 7) * 8));
            const half8 vr = *(const half8*)&SrT[idx];
            const half8 vi = *(const half8*)&SiT[idx];
            const int ktr = bx * 2 + kt2l;                     // Sr k-tile
            const int kti = 17 + ktr;                          // Si k-tile
            *(half8*)(A2 + ((((size_t)mblk * 34 + ktr) * 8 + mts) * 64 + l) * 8) = vr;
            *(half8*)(A2 + ((((size_t)mblk * 34 + kti) * 8 + mts) * 64 + l) * 8) = vi;
        }
    }
}

// ---------------- GEMM2: mirror-symmetric frames = A2 @ basis ---------------
// Round-12 structure (best measured): 2-kt steps, scalar mirror epilogue into
// frames[16384][1024].

__device__ __forceinline__ void mma43(const _Float16* __restrict__ As,
                                      const _Float16* __restrict__ Bs,
                                      int wm, int wn, int lane16, f32x4 (&acc)[4][3])
{
    half8 a[4], b[3];
#pragma unroll
    for (int i = 0; i < 4; ++i) a[i] = *(const half8*)&As[(wm + i) * 512 + lane16];
#pragma unroll
    for (int j = 0; j < 3; ++j) b[j] = *(const half8*)&Bs[(wn + j) * 512 + lane16];
#pragma unroll
    for (int i = 0; i < 4; ++i)
#pragma unroll
        for (int j = 0; j < 3; ++j)
            acc[i][j] = __builtin_amdgcn_mfma_f32_16x16x32_f16(a[i], b[j], acc[i][j], 0, 0, 0);
}

__global__ __launch_bounds__(256, 3)
void gemm2_k(const _Float16* __restrict__ A, const _Float16* __restrict__ Bas,
             _Float16* __restrict__ C)
{
    __shared__ _Float16 As[2][8 * 512];   // 2 k-tiles x 128 m-rows
    __shared__ _Float16 Bs[2][6 * 512];   // 2 k-tiles x 96 n-cols
    const int t = threadIdx.x, w = t >> 6, l = t & 63;

    // XCD-aware swizzle: 768 blocks, 96 per XCD = 16 mblk x 6 nblk.
    const int lin = blockIdx.x;
    const int xcd = lin & 7, slot = lin >> 3;
    const int mblk = xcd * 16 + slot / 6;   // [0,128)
    const int nblk = slot % 6;              // [0,6)

    const int wm = (w & 1) * 4, wn = (w >> 1) * 3;

    f32x4 accC[4][3], accD[4][3];
#pragma unroll
    for (int i = 0; i < 4; ++i)
#pragma unroll
        for (int j = 0; j < 3; ++j) { accC[i][j] = (f32x4)0.0f; accD[i][j] = (f32x4)0.0f; }

    const int lane16 = l * 8;

    for (int step = 0; step < 17; ++step) {
        const int kt0 = 2 * step;
        __syncthreads();
#pragma unroll
        for (int i = 0; i < 4; ++i) {
            const int ta = 4 * w + i;
            const int u = ta >> 3, mts = ta & 7;
            const _Float16* Ag = A + ((((size_t)mblk * 34 + (kt0 + u)) * 8 + mts) * 512) + lane16;
            stage16(Ag, &As[u][mts * 512]);
        }
#pragma unroll
        for (int i = 0; i < 3; ++i) {
            const int tb = 3 * w + i;
            const int u = tb / 6, nt = tb % 6;
            const _Float16* Bg = Bas + ((((size_t)nblk * 34 + (kt0 + u)) * 6 + nt) * 512) + lane16;
            stage16(Bg, &Bs[u][nt * 512]);
        }
        __syncthreads();

#pragma unroll
        for (int u = 0; u < 2; ++u) {
            const int kt = kt0 + u;
            if (kt < 17) mma43(As[u], Bs[u], wm, wn, lane16, accC);
            else         mma43(As[u], Bs[u], wm, wn, lane16, accD);
        }
    }

    // epilogue: frames[n] = C+D, frames[1024-n] = C-D  (hann(1024-n)=hann(n))
    const int r4 = (l >> 4) * 4, c0 = l & 15;
#pragma unroll
    for (int i = 0; i < 4; ++i) {
        const int m = mblk * 128 + (wm + i) * 16 + r4;
#pragma unroll
        for (int j = 0; j < 3; ++j) {
            const int n = nblk * 96 + (wn + j) * 16 + c0;
#pragma unroll
            for (int r = 0; r < 4; ++r) {
                const float cv = accC[i][j][r];
                const float dv = accD[i][j][r];
                _Float16* row = C + (size_t)(m + r) * 1024;
                if (n < 513)           row[n]        = (_Float16)(cv + dv);
                if (n >= 1 && n < 512) row[1024 - n] = (_Float16)(cv - dv);
            }
        }
    }
}

// ---------------- overlap-add + envelope ------------------------------------
// Interior samples (j0 in [640, 523904)): exactly 4 taps at s = nb, nb+256,
// nb+512, nb+768 in rows T, T-1, T-2, T-3 — env == 1.5 EXACTLY (75%-overlap
// hann identity) => 4 coalesced half8 loads + f32 sum * 2/3, f32x4 stores.
// Boundary samples: round-12 general loop (trig env), reference semantics.

__global__ __launch_bounds__(256)
void ola_kernel(const _Float16* __restrict__ frames, float* __restrict__ out)
{
    const int gid = blockIdx.x * 256 + threadIdx.x;     // [0, 524288)
    const size_t base = (size_t)gid * 8;
    const int b  = (int)(base >> 19);
    const int j0 = (int)(base & 524287);
    const int n0 = j0 + 384;

    if (j0 >= 640 && j0 < 523904) {
        const int nb = n0 & 255;                        // <= 248, 8-aligned
        const int T  = n0 >> 8;
        const size_t rT = ((size_t)(b * 2048 + T)) << 10;
        const half8 v0 = *(const half8*)(frames + rT + nb);
        const half8 v1 = *(const half8*)(frames + rT - 1024 + nb + 256);
        const half8 v2 = *(const half8*)(frames + rT - 2048 + nb + 512);
        const half8 v3 = *(const half8*)(frames + rT - 3072 + nb + 768);
        f32x4 o0, o1;
#pragma unroll
        for (int e = 0; e < 4; ++e)
            o0[e] = ((float)v0[e] + (float)v1[e] + (float)v2[e] + (float)v3[e]) * (2.0f / 3.0f);
#pragma unroll
        for (int e = 0; e < 4; ++e)
            o1[e] = ((float)v0[4 + e] + (float)v1[4 + e] + (float)v2[4 + e] + (float)v3[4 + e]) * (2.0f / 3.0f);
        *(f32x4*)(out + base) = o0;
        *(f32x4*)(out + base + 4) = o1;
    } else {
        for (int e = 0; e < 8; ++e) {
            const int n = n0 + e;
            int t_hi = n >> 8;
            if (t_hi > 2047) t_hi = 2047;
            const int t_lo = (n >= 1023) ? ((n - 1023 + 255) >> 8) : 0;
            float acc = 0.0f, env = 0.0f;
            for (int tt = t_lo; tt <= t_hi; ++tt) {
                const int s = n - (tt << 8);
                const float wv = hannf(s);
                acc += (float)frames[(((size_t)(b * 2048 + tt)) << 10) + s];
                env += wv * wv;
            }
            out[base + e] = acc / env;
        }
    }
}

// ---------------- launch ----------------------------------------------------

extern "C" void kernel_launch(void* const* d_in, const int* in_sizes, int n_in,
                              void* d_out, int out_size, void* d_ws, size_t ws_size,
                              hipStream_t stream)
{
    const float* x = (const float*)d_in[0];   // 16384 x 512
    const float* W = (const float*)d_in[1];   // 512 x 1026
    const float* b = (const float*)d_in[2];   // 1026
    float* out = (float*)d_out;               // 8 x 524288
    char* ws = (char*)d_ws;

    _Float16* A2 = (_Float16*)(ws + OFF_A2);
    _Float16* B2 = (_Float16*)(ws + OFF_B2);
    _Float16* A1 = (_Float16*)(ws + OFF_A1);
    _Float16* B1 = (_Float16*)(ws + OFF_B1);
    _Float16* frames = (_Float16*)(ws + OFF_FR);

    prep_k<<<4690, 256, 0, stream>>>(x, W, A1, B1, B2);

    gemm1_k<<<1152, 256, 0, stream>>>(A1, B1, b, A2);
    gemm2_k<<<768, 256, 0, stream>>>(A2, B2, frames);

    ola_kernel<<<out_size / 2048, 256, 0, stream>>>(frames, out);
}